// Round 2
// baseline (12531.196 us; speedup 1.0000x reference)
//
#include <hip/hip_runtime.h>
#include <cmath>

// Problem constants (match reference)
constexpr int   B        = 4;
constexpr int   P        = 2048;   // P1 == P2
constexpr int   D        = 64;
constexpr float EPS      = 0.1f;
constexpr float THRESH   = 0.1f;
constexpr int   MAX_ITER = 100;

constexpr float LOG2E   = 1.44269504088896340736f;
constexpr float LN2     = 0.69314718055994530942f;
constexpr float SCALE   = LOG2E / EPS;   // natural -> log2 domain, /eps folded in
constexpr float UNSCALE = EPS * LN2;     // inverse

// ws layout (floats): u2s[8192] @0 | v2s[8192] @8192 | uo[8192] @16384 | err[128] @24576
constexpr int WS_U   = 0;
constexpr int WS_V   = 8192;
constexpr int WS_UO  = 16384;
constexpr int WS_ERR = 24576;
constexpr int WS_FLOATS = 24704;

// ============ prep: C = sum_d (x-y)^2 ; zero scratch + cost ============
// 256 blocks x 256 thr. Block: bb=bid>>6, rows [rc*32, rc*32+32) of batch bb.
__global__ __launch_bounds__(256)
void prep_kernel(const float* __restrict__ x, const float* __restrict__ y,
                 float* __restrict__ out, float* __restrict__ ws)
{
    const int bid = blockIdx.x, tid = threadIdx.x;
    const int w = tid >> 6, l = tid & 63;
    const int bb = bid >> 6, rc = bid & 63;
    const int row0 = rc * 32;

    if (bid == 0) {
        for (int i = tid; i < WS_FLOATS; i += 256) ws[i] = 0.0f;
        if (tid < B) out[tid] = 0.0f;                 // cost slots
    }

    float* C_out = out + B + (size_t)B * P * P;

    __shared__ float smem[64 * 129 + 32 * 64];        // y^T (padded) + x tile
    float* y_lds = smem;
    float* x_lds = smem + 64 * 129;

    for (int i = tid; i < 32 * D; i += 256)
        x_lds[i] = x[(size_t)(bb * P + row0) * D + i];
    __syncthreads();

    for (int ch = 0; ch < 16; ++ch) {                 // 128 cols per chunk
        const int col0 = ch * 128;
        for (int i = tid; i < 128 * D; i += 256) {    // transpose y into LDS
            int c = i >> 6, d = i & 63;
            y_lds[d * 129 + c] = y[(size_t)(bb * P + col0) * D + i];
        }
        __syncthreads();
        #pragma unroll
        for (int r = 0; r < 8; ++r) {
            const int R = w * 8 + r;
            #pragma unroll
            for (int kk = 0; kk < 2; ++kk) {
                const int c = kk * 64 + l;
                float acc = 0.0f;
                #pragma unroll
                for (int d = 0; d < D; ++d) {
                    float diff = x_lds[R * D + d] - y_lds[d * 129 + c];
                    acc = fmaf(diff, diff, acc);
                }
                C_out[(size_t)(bb * P + row0 + R) * P + col0 + c] = acc;
            }
        }
        __syncthreads();
    }
}

// ============ u-pass: u_i = A - eps*ln2*(log2 sum_j 2^(v2_j - SCALE*C_ij)) ============
// 2048 blocks x 256 thr; one row per wave; lane l owns cols l+64k, k<32 (in regs).
__global__ __launch_bounds__(256)
void upass_kernel(const float* __restrict__ C, float* __restrict__ ws, int t)
{
    float* u2s = ws + WS_U;
    float* v2s = ws + WS_V;
    float* uo  = ws + WS_UO;
    float* err = ws + WS_ERR;
    if (t > 0 && err[t - 1] < 4.0f * THRESH) return;  // frozen (emulates break)

    const int w = threadIdx.x >> 6, l = threadIdx.x & 63;
    const int row = blockIdx.x * 4 + w;               // 0..8191 global row
    const int bb  = row >> 11;
    const float* Crow = C + (size_t)row * P;
    const float* v2   = v2s + bb * P;

    const float A = EPS * __logf(1.0f / (float)P + 1e-8f);

    float tv[32];
    float M = -1e30f;
    #pragma unroll
    for (int k = 0; k < 32; ++k) {
        float tt = v2[l + 64 * k] - SCALE * Crow[l + 64 * k];
        tv[k] = tt;
        M = fmaxf(M, tt);
    }
    #pragma unroll
    for (int off = 1; off < 64; off <<= 1) M = fmaxf(M, __shfl_xor(M, off));
    float s = 0.0f;
    #pragma unroll
    for (int k = 0; k < 32; ++k) s += exp2f(tv[k] - M);
    #pragma unroll
    for (int off = 1; off < 64; off <<= 1) s += __shfl_xor(s, off);

    float u_nat = A - UNSCALE * (M + log2f(s));

    __shared__ float sm[4];
    if (l == 0) {
        sm[w] = fabsf(u_nat - uo[row]);
        uo[row]  = u_nat;
        u2s[row] = u_nat * SCALE;
    }
    __syncthreads();
    if (threadIdx.x == 0)
        atomicAdd(&err[t], sm[0] + sm[1] + sm[2] + sm[3]);
}

// ============ v-pass: v_j = A - eps*ln2*(log2 sum_i 2^(u2_i - SCALE*C_ij)) ============
// 256 blocks x 256 thr; block: 32 cols of one batch. Thread (g=tid>>5, c=tid&31):
// column j0+c, rows i = g + 8k. 8 register-chunks of 32 rows -> ~1 exp2/elem.
__global__ __launch_bounds__(256)
void vpass_kernel(const float* __restrict__ C, float* __restrict__ ws, int t)
{
    float* u2s = ws + WS_U;
    float* v2s = ws + WS_V;
    float* err = ws + WS_ERR;
    if (t > 0 && err[t - 1] < 4.0f * THRESH) return;

    const int bid = blockIdx.x;
    const int bb  = bid >> 6;
    const int j0  = (bid & 63) * 32;
    const int c   = threadIdx.x & 31;
    const int g   = threadIdx.x >> 5;                 // 0..7
    const float* u2 = u2s + bb * P;
    const float* Cb = C + (size_t)bb * P * P;

    const float A = EPS * __logf(1.0f / (float)P + 1e-8f);

    float m = -1e30f, s = 0.0f;
    for (int ch = 0; ch < 8; ++ch) {
        float tv[32];
        float mc = -1e30f;
        #pragma unroll
        for (int k = 0; k < 32; ++k) {
            const int i = g + 8 * (ch * 32 + k);
            float tt = u2[i] - SCALE * Cb[(size_t)i * P + j0 + c];
            tv[k] = tt;
            mc = fmaxf(mc, tt);
        }
        float m2 = fmaxf(m, mc);
        float sc = 0.0f;
        #pragma unroll
        for (int k = 0; k < 32; ++k) sc += exp2f(tv[k] - m2);
        s = fmaf(s, exp2f(m - m2), sc);
        m = m2;
    }

    __shared__ float sm[512];
    sm[threadIdx.x * 2]     = m;
    sm[threadIdx.x * 2 + 1] = s;
    __syncthreads();
    if (threadIdx.x < 32) {
        float M = sm[threadIdx.x * 2], S = sm[threadIdx.x * 2 + 1];
        #pragma unroll
        for (int q = 1; q < 8; ++q) {
            float pm = sm[(q * 32 + threadIdx.x) * 2];
            float ps = sm[(q * 32 + threadIdx.x) * 2 + 1];
            float m2 = fmaxf(M, pm);
            S = fmaf(S, exp2f(M - m2), ps * exp2f(pm - m2));
            M = m2;
        }
        float v_nat = A - UNSCALE * (M + log2f(S));
        v2s[bb * P + j0 + threadIdx.x] = v_nat * SCALE;
    }
}

// ============ epilogue: pi = exp((u+v-C)/eps), cost = sum pi*C ============
// 256 blocks x 256 thr; same tiling as prep.
__global__ __launch_bounds__(256)
void epi_kernel(float* __restrict__ out, const float* __restrict__ ws)
{
    const float* u2s = ws + WS_U;
    const float* v2s = ws + WS_V;
    float* cost = out;
    float* pi   = out + B;
    const float* C = out + B + (size_t)B * P * P;

    const int bid = blockIdx.x, tid = threadIdx.x;
    const int w = tid >> 6, l = tid & 63;
    const int bb = bid >> 6, row0 = (bid & 63) * 32;

    float v2[32];
    #pragma unroll
    for (int k = 0; k < 32; ++k) v2[k] = v2s[bb * P + k * 64 + l];

    float lc = 0.0f;
    for (int r = 0; r < 8; ++r) {
        const int row = row0 + w * 8 + r;
        const size_t base = (size_t)(bb * P + row) * P;
        const float ur = u2s[bb * P + row];
        #pragma unroll
        for (int k = 0; k < 32; ++k) {
            float Cv = C[base + k * 64 + l];
            float p  = exp2f(ur + v2[k] - SCALE * Cv);
            lc = fmaf(p, Cv, lc);
            pi[base + k * 64 + l] = p;
        }
    }
    #pragma unroll
    for (int off = 1; off < 64; off <<= 1) lc += __shfl_xor(lc, off);
    __shared__ float sm[4];
    if (l == 0) sm[w] = lc;
    __syncthreads();
    if (tid == 0) atomicAdd(&cost[bb], sm[0] + sm[1] + sm[2] + sm[3]);
}

extern "C" void kernel_launch(void* const* d_in, const int* in_sizes, int n_in,
                              void* d_out, int out_size, void* d_ws, size_t ws_size,
                              hipStream_t stream) {
    const float* x = (const float*)d_in[0];
    const float* y = (const float*)d_in[1];
    float* out = (float*)d_out;
    float* ws  = (float*)d_ws;
    const float* C = out + B + (size_t)B * P * P;

    prep_kernel<<<256, 256, 0, stream>>>(x, y, out, ws);
    for (int t = 0; t < MAX_ITER; ++t) {
        upass_kernel<<<2048, 256, 0, stream>>>(C, ws, t);
        vpass_kernel<<<256,  256, 0, stream>>>(C, ws, t);
    }
    epi_kernel<<<256, 256, 0, stream>>>(out, ws);
}

// Round 3
// 7699.927 us; speedup vs baseline: 1.6274x; 1.6274x over previous
//
#include <hip/hip_runtime.h>
#include <cmath>

// Problem constants (match reference)
constexpr int   B        = 4;
constexpr int   P        = 2048;   // P1 == P2
constexpr int   D        = 64;
constexpr float EPS      = 0.1f;
constexpr float THRESH   = 0.1f;
constexpr int   MAX_ITER = 100;

constexpr float LOG2E   = 1.44269504088896340736f;
constexpr float LN2     = 0.69314718055994530942f;
constexpr float SCALE   = LOG2E / EPS;   // natural -> log2 domain, /eps folded in
constexpr float UNSCALE = EPS * LN2;     // inverse

// ws layout (floats): u2s[8192] | v2s[8192] | uo[8192] | err[128]   (~99 KB, proven OK)
constexpr int WS_U   = 0;
constexpr int WS_V   = 8192;
constexpr int WS_UO  = 16384;
constexpr int WS_ERR = 24576;
constexpr int WS_FLOATS = 24704;

__device__ __forceinline__ float max4(float4 a) {
    return fmaxf(fmaxf(a.x, a.y), fmaxf(a.z, a.w));
}

// ============ prep: C = sum_d (x-y)^2, register-tiled; zero scratch ============
// grid 2048 = B * 32 * 16. Block tile: 64 rows x 128 cols. Thread (tx=tid&15,
// ty=tid>>4) computes rows ty*4+j, cols tx*8+i -> 32 FMA per 12 LDS reads.
__global__ __launch_bounds__(256)
void prep_kernel(const float* __restrict__ x, const float* __restrict__ y,
                 float* __restrict__ out, float* __restrict__ ws)
{
    const int bid = blockIdx.x, tid = threadIdx.x;
    const int bb = bid >> 9, tr = (bid >> 4) & 31, tc = bid & 15;
    const int row0 = tr * 64, col0 = tc * 128;

    if (bid == 0) {
        for (int i = tid; i < WS_FLOATS; i += 256) ws[i] = 0.0f;
        if (tid < B) out[tid] = 0.0f;
    }

    __shared__ float xs[64 * 65];
    __shared__ float ys[128 * 65];
    for (int i = tid; i < 64 * 64; i += 256) {
        int r = i >> 6, d = i & 63;
        xs[r * 65 + d] = x[(size_t)(bb * P + row0 + r) * D + d];
    }
    for (int i = tid; i < 128 * 64; i += 256) {
        int c = i >> 6, d = i & 63;
        ys[c * 65 + d] = y[(size_t)(bb * P + col0 + c) * D + d];
    }
    __syncthreads();

    const int tx = tid & 15, ty = tid >> 4;
    float acc[4][8];
    #pragma unroll
    for (int j = 0; j < 4; ++j)
        #pragma unroll
        for (int i = 0; i < 8; ++i) acc[j][i] = 0.0f;

    #pragma unroll 4
    for (int k = 0; k < 64; ++k) {
        float xa[4], yb[8];
        #pragma unroll
        for (int j = 0; j < 4; ++j) xa[j] = xs[(ty * 4 + j) * 65 + k];
        #pragma unroll
        for (int i = 0; i < 8; ++i) yb[i] = ys[(tx * 8 + i) * 65 + k];
        #pragma unroll
        for (int j = 0; j < 4; ++j)
            #pragma unroll
            for (int i = 0; i < 8; ++i) {
                float d = xa[j] - yb[i];
                acc[j][i] = fmaf(d, d, acc[j][i]);
            }
    }

    float* C_out = out + B + (size_t)B * P * P;
    #pragma unroll
    for (int j = 0; j < 4; ++j) {
        size_t base = (size_t)(bb * P + row0 + ty * 4 + j) * P + col0 + tx * 8;
        float4 a0 = make_float4(acc[j][0], acc[j][1], acc[j][2], acc[j][3]);
        float4 a1 = make_float4(acc[j][4], acc[j][5], acc[j][6], acc[j][7]);
        ((float4*)&C_out[base])[0] = a0;
        ((float4*)&C_out[base])[1] = a1;
    }
}

// ============ fused iteration: u-update + v-column-partials, C read ONCE ============
// grid 512 = B*128. Block owns 16 rows x 2048 cols (128 KB of C) in registers:
// wave w rows w*4+j; lane l float4-cols l+64k (k<8). u for a row needs only old v;
// v-partials need only this block's fresh u -> no inter-block sync inside.
__global__ __launch_bounds__(256, 2)
void iter_kernel(const float* __restrict__ C, float* __restrict__ part_m,
                 float* __restrict__ part_s, float* __restrict__ ws, int t)
{
    float* u2s = ws + WS_U;
    float* v2s = ws + WS_V;
    float* uo  = ws + WS_UO;
    float* err = ws + WS_ERR;
    if (t > 0 && err[t - 1] < 4.0f * THRESH) return;   // frozen (emulates break)

    const int bid = blockIdx.x, tid = threadIdx.x;
    const int w = tid >> 6, l = tid & 63;
    const int bb = bid >> 7, rc = bid & 127;
    const int row0 = rc * 16;
    const int baserow = bb * P + row0 + w * 4;         // index into [B*P] arrays

    __shared__ float4 m_lds[4 * 512];                  // 32 KB
    __shared__ float4 s_lds[4 * 512];                  // 32 KB

    const float A = EPS * __logf(1.0f / (float)P + 1e-8f);

    // old v (pre-scaled) for this lane's 32 columns
    const float4* vv = (const float4*)(v2s + bb * P);
    float4 v4[8];
    #pragma unroll
    for (int k = 0; k < 8; ++k) v4[k] = vv[l + 64 * k];

    // load C tile, pre-scaled: c2 = -C/eps*log2e
    float4 c2[4][8];
    #pragma unroll
    for (int j = 0; j < 4; ++j) {
        const float4* Crow = (const float4*)(C + (size_t)(baserow + j) * P);
        #pragma unroll
        for (int k = 0; k < 8; ++k) {
            float4 cc = Crow[l + 64 * k];
            c2[j][k] = make_float4(-SCALE * cc.x, -SCALE * cc.y,
                                   -SCALE * cc.z, -SCALE * cc.w);
        }
    }

    // ---- u update per row (exact max-then-sum LSE) ----
    float u2row[4];
    float dsum = 0.0f;
    #pragma unroll
    for (int j = 0; j < 4; ++j) {
        float m = -1e30f;
        #pragma unroll
        for (int k = 0; k < 8; ++k) {
            float4 tt = make_float4(v4[k].x + c2[j][k].x, v4[k].y + c2[j][k].y,
                                    v4[k].z + c2[j][k].z, v4[k].w + c2[j][k].w);
            m = fmaxf(m, max4(tt));
        }
        #pragma unroll
        for (int off = 1; off < 64; off <<= 1) m = fmaxf(m, __shfl_xor(m, off));
        float s = 0.0f;
        #pragma unroll
        for (int k = 0; k < 8; ++k) {
            s += exp2f(v4[k].x + c2[j][k].x - m) + exp2f(v4[k].y + c2[j][k].y - m)
               + exp2f(v4[k].z + c2[j][k].z - m) + exp2f(v4[k].w + c2[j][k].w - m);
        }
        #pragma unroll
        for (int off = 1; off < 64; off <<= 1) s += __shfl_xor(s, off);
        float u_nat = A - UNSCALE * (m + log2f(s));
        u2row[j] = u_nat * SCALE;
        if (l == 0) {
            const int rg = baserow + j;
            dsum += fabsf(u_nat - uo[rg]);
            uo[rg]  = u_nat;
            u2s[rg] = u2row[j];
        }
    }
    if (l == 0) atomicAdd(&err[t], dsum);              // one per wave

    // ---- v partials over this wave's 4 rows (fresh u) ----
    #pragma unroll
    for (int k = 0; k < 8; ++k) {
        float4 t0 = make_float4(u2row[0] + c2[0][k].x, u2row[0] + c2[0][k].y,
                                u2row[0] + c2[0][k].z, u2row[0] + c2[0][k].w);
        float4 t1 = make_float4(u2row[1] + c2[1][k].x, u2row[1] + c2[1][k].y,
                                u2row[1] + c2[1][k].z, u2row[1] + c2[1][k].w);
        float4 t2 = make_float4(u2row[2] + c2[2][k].x, u2row[2] + c2[2][k].y,
                                u2row[2] + c2[2][k].z, u2row[2] + c2[2][k].w);
        float4 t3 = make_float4(u2row[3] + c2[3][k].x, u2row[3] + c2[3][k].y,
                                u2row[3] + c2[3][k].z, u2row[3] + c2[3][k].w);
        float4 pm, ps;
        pm.x = fmaxf(fmaxf(t0.x, t1.x), fmaxf(t2.x, t3.x));
        pm.y = fmaxf(fmaxf(t0.y, t1.y), fmaxf(t2.y, t3.y));
        pm.z = fmaxf(fmaxf(t0.z, t1.z), fmaxf(t2.z, t3.z));
        pm.w = fmaxf(fmaxf(t0.w, t1.w), fmaxf(t2.w, t3.w));
        ps.x = exp2f(t0.x - pm.x) + exp2f(t1.x - pm.x) + exp2f(t2.x - pm.x) + exp2f(t3.x - pm.x);
        ps.y = exp2f(t0.y - pm.y) + exp2f(t1.y - pm.y) + exp2f(t2.y - pm.y) + exp2f(t3.y - pm.y);
        ps.z = exp2f(t0.z - pm.z) + exp2f(t1.z - pm.z) + exp2f(t2.z - pm.z) + exp2f(t3.z - pm.z);
        ps.w = exp2f(t0.w - pm.w) + exp2f(t1.w - pm.w) + exp2f(t2.w - pm.w) + exp2f(t3.w - pm.w);
        m_lds[w * 512 + l + 64 * k] = pm;
        s_lds[w * 512 + l + 64 * k] = ps;
    }
    __syncthreads();

    // ---- cross-wave merge -> block partial (2048 cols) ----
    float4* pm_out = ((float4*)part_m) + (size_t)bid * 512;
    float4* ps_out = ((float4*)part_s) + (size_t)bid * 512;
    #pragma unroll
    for (int h = 0; h < 2; ++h) {
        const int idx = tid * 2 + h;                   // float4 column index 0..511
        float4 M = m_lds[idx], S = s_lds[idx];
        #pragma unroll
        for (int q = 1; q < 4; ++q) {
            float4 pm = m_lds[q * 512 + idx], ps = s_lds[q * 512 + idx];
            float m2;
            m2 = fmaxf(M.x, pm.x); S.x = S.x * exp2f(M.x - m2) + ps.x * exp2f(pm.x - m2); M.x = m2;
            m2 = fmaxf(M.y, pm.y); S.y = S.y * exp2f(M.y - m2) + ps.y * exp2f(pm.y - m2); M.y = m2;
            m2 = fmaxf(M.z, pm.z); S.z = S.z * exp2f(M.z - m2) + ps.z * exp2f(pm.z - m2); M.z = m2;
            m2 = fmaxf(M.w, pm.w); S.w = S.w * exp2f(M.w - m2) + ps.w * exp2f(pm.w - m2); M.w = m2;
        }
        pm_out[idx] = M;
        ps_out[idx] = S;
    }
}

// ============ combine: fold 128 chunk-partials per column -> v ============
// grid 32 x 256; one thread per global column.
__global__ __launch_bounds__(256)
void comb_kernel(const float* __restrict__ part_m, const float* __restrict__ part_s,
                 float* __restrict__ ws, int t)
{
    float* v2s = ws + WS_V;
    float* err = ws + WS_ERR;
    if (t > 0 && err[t - 1] < 4.0f * THRESH) return;

    const int g = blockIdx.x * 256 + threadIdx.x;      // 0..8191
    const int b = g >> 11, c = g & (P - 1);
    const float* pmb = part_m + (size_t)(b * 128) * P + c;
    const float* psb = part_s + (size_t)(b * 128) * P + c;

    const float A = EPS * __logf(1.0f / (float)P + 1e-8f);

    float M = -1e30f;
    #pragma unroll 8
    for (int q = 0; q < 128; ++q) M = fmaxf(M, pmb[(size_t)q * P]);
    float S = 0.0f;
    #pragma unroll 8
    for (int q = 0; q < 128; ++q)
        S = fmaf(psb[(size_t)q * P], exp2f(pmb[(size_t)q * P] - M), S);

    float v_nat = A - UNSCALE * (M + log2f(S));
    v2s[g] = v_nat * SCALE;
}

// ============ epilogue: pi = exp((u+v-C)/eps), cost = sum pi*C ============
// grid 512, same tiling as iter, fully float4.
__global__ __launch_bounds__(256)
void epi_kernel(float* __restrict__ out, const float* __restrict__ ws)
{
    const float* u2s = ws + WS_U;
    const float* v2s = ws + WS_V;
    float* cost = out;
    float* pi   = out + B;
    const float* C = out + B + (size_t)B * P * P;

    const int bid = blockIdx.x, tid = threadIdx.x;
    const int w = tid >> 6, l = tid & 63;
    const int bb = bid >> 7, rc = bid & 127;
    const int row0 = rc * 16;

    const float4* vv = (const float4*)(v2s + bb * P);
    float4 v4[8];
    #pragma unroll
    for (int k = 0; k < 8; ++k) v4[k] = vv[l + 64 * k];

    float lc = 0.0f;
    #pragma unroll
    for (int j = 0; j < 4; ++j) {
        const int r = row0 + w * 4 + j;
        const float u2 = u2s[bb * P + r];
        const float4* Crow = (const float4*)(C  + (size_t)(bb * P + r) * P);
        float4*       Prow = (float4*)      (pi + (size_t)(bb * P + r) * P);
        #pragma unroll
        for (int k = 0; k < 8; ++k) {
            float4 cc = Crow[l + 64 * k];
            float4 p;
            p.x = exp2f(u2 + v4[k].x - SCALE * cc.x);
            p.y = exp2f(u2 + v4[k].y - SCALE * cc.y);
            p.z = exp2f(u2 + v4[k].z - SCALE * cc.z);
            p.w = exp2f(u2 + v4[k].w - SCALE * cc.w);
            lc = fmaf(p.x, cc.x, lc); lc = fmaf(p.y, cc.y, lc);
            lc = fmaf(p.z, cc.z, lc); lc = fmaf(p.w, cc.w, lc);
            Prow[l + 64 * k] = p;
        }
    }
    #pragma unroll
    for (int off = 1; off < 64; off <<= 1) lc += __shfl_xor(lc, off);
    __shared__ float sm[4];
    if (l == 0) sm[w] = lc;
    __syncthreads();
    if (tid == 0) atomicAdd(&cost[bb], sm[0] + sm[1] + sm[2] + sm[3]);
}

extern "C" void kernel_launch(void* const* d_in, const int* in_sizes, int n_in,
                              void* d_out, int out_size, void* d_ws, size_t ws_size,
                              hipStream_t stream) {
    const float* x = (const float*)d_in[0];
    const float* y = (const float*)d_in[1];
    float* out = (float*)d_out;
    float* ws  = (float*)d_ws;
    const float* C = out + B + (size_t)B * P * P;
    // chunk partials live in the pi region (overwritten by epi): 2 x 4 MB
    float* part_m = out + B;
    float* part_s = part_m + 512 * P;

    prep_kernel<<<2048, 256, 0, stream>>>(x, y, out, ws);
    for (int t = 0; t < MAX_ITER; ++t) {
        iter_kernel<<<512, 256, 0, stream>>>(C, part_m, part_s, ws, t);
        comb_kernel<<<32,  256, 0, stream>>>(part_m, part_s, ws, t);
    }
    epi_kernel<<<512, 256, 0, stream>>>(out, ws);
}